// Round 3
// baseline (330.897 us; speedup 1.0000x reference)
//
#include <hip/hip_runtime.h>

// GeneralConvNd (7x7, Cin=1, Cout=64, 'same') as implicit GEMM, no-LDS version.
// out[b,h,w,c] = sum_{ky,kx} x[b,h+ky-3,w+kx-3] * W[ky*7+kx,c] + bias[c]
//
// Tap re-index (k-permutation cancels between A and B frags): t = ky*8+kx,
// t in [0,64); kx==7 or ky==7 are dummy taps with W=0 (x value finite garbage).
// Per lane (lq=lane>>4, lr=lane&15), frag element (ch,j): ky=ch*4+lq, kx=j
// -> each chunk's 8 x-values are 8 CONSECUTIVE floats of one row: 2x16B loads.
//
// MFMA operands swapped vs classic: A = W^T (chan x k), B = patches (k x px),
// D[chan][px]: chan = g*16 + lq*4 + reg, px = w0 + lr  ->  per-lane acc is 4
// consecutive channels at one pixel => 4x global_store_dwordx4 per wave-tile.
// W-frags (32 VGPR) + bias (16 VGPR) loaded once per wave, amortized over 9
// grid-strided tiles. No LDS, no barriers. Purely write-BW-bound (~302 MB out).

#define HH 384
#define WW 384
#define BB 8
#define CC 64
#define TPW 16                         // pixels per wave-tile
#define TROW (WW / TPW)                // 24 tiles per image row
#define NTILES (BB * HH * TROW)        // 73728
#define NBLOCKS 2048
#define WPB 4
#define NWAVES (NBLOCKS * WPB)         // 8192
#define TPWAVE (NTILES / NWAVES)       // 9 exactly

typedef __attribute__((ext_vector_type(8))) __bf16 bf16x8;
typedef __attribute__((ext_vector_type(4))) float f32x4;

__global__ __launch_bounds__(256)
void conv7_mfma_nolds(const float* __restrict__ xg, const float* __restrict__ wg,
                      const float* __restrict__ bg, float* __restrict__ out)
{
    const int tid  = threadIdx.x;
    const int lane = tid & 63;
    const int wv   = tid >> 6;
    const int lq   = lane >> 4;   // 0..3
    const int lr   = lane & 15;   // 0..15

    // ---- A-operand (W^T) fragments + bias: once per wave ----
    bf16x8 wfr[2][4];
#pragma unroll
    for (int ch = 0; ch < 2; ++ch)
#pragma unroll
        for (int g = 0; g < 4; ++g) {
            bf16x8 f;
#pragma unroll
            for (int j = 0; j < 8; ++j) {
                const int ky = ch * 4 + lq;          // 0..7
                const int kx = j;                    // 0..7
                f[j] = (ky < 7 && kx < 7) ? (__bf16)wg[(ky * 7 + kx) * CC + g * 16 + lr]
                                          : (__bf16)0.f;
            }
            wfr[ch][g] = f;
        }
    f32x4 biasf[4];
#pragma unroll
    for (int g = 0; g < 4; ++g)
        biasf[g] = *(const f32x4*)(bg + g * 16 + lq * 4);   // 16B-aligned

    const int gw = blockIdx.x * WPB + wv;

    for (int it = 0; it < TPWAVE; ++it) {
        const int tile = gw * TPWAVE + it;           // consecutive -> L1 reuse of x
        const int tw = tile % TROW;
        const int rh = tile / TROW;
        const int h  = rh % HH;
        const int b  = rh / HH;
        const int w0 = tw * TPW;

        // ---- B-operand (patches) fragments, straight from global ----
        bf16x8 xf[2];
        const bool interior = (h >= 3) & (h <= HH - 5) & (w0 != 0) & (w0 != WW - TPW);
        if (interior) {
            const float* p0 = xg + ((size_t)b * HH + (h - 3)) * WW + (w0 - 3 + lr);
#pragma unroll
            for (int ch = 0; ch < 2; ++ch) {
                float v[8];
                __builtin_memcpy(v, p0 + (size_t)(ch * 4 + lq) * WW, 32);
                bf16x8 f;
#pragma unroll
                for (int j = 0; j < 8; ++j) f[j] = (__bf16)v[j];
                xf[ch] = f;
            }
        } else {
#pragma unroll
            for (int ch = 0; ch < 2; ++ch) {
                const int r  = h - 3 + ch * 4 + lq;
                const int rc = r < 0 ? 0 : (r > HH - 1 ? HH - 1 : r);
                const bool rok = (r >= 0) & (r < HH);
                const float* prow = xg + ((size_t)b * HH + rc) * WW;
                bf16x8 f;
#pragma unroll
                for (int j = 0; j < 8; ++j) {
                    const int c  = w0 - 3 + lr + j;
                    const int cc = c < 0 ? 0 : (c > WW - 1 ? WW - 1 : c);
                    float v = prow[cc];                       // always in-bounds
                    v = (rok & (c >= 0) & (c < WW)) ? v : 0.f; // cndmask, no branch
                    f[j] = (__bf16)v;
                }
                xf[ch] = f;
            }
        }

        f32x4 acc[4];
#pragma unroll
        for (int g = 0; g < 4; ++g) acc[g] = biasf[g];
#pragma unroll
        for (int ch = 0; ch < 2; ++ch)
#pragma unroll
            for (int g = 0; g < 4; ++g)
                acc[g] = __builtin_amdgcn_mfma_f32_16x16x32_bf16(
                    wfr[ch][g], xf[ch], acc[g], 0, 0, 0);

        // ---- store: 4 consecutive chans per lane -> dwordx4 ----
        float* op = out + (((size_t)b * HH + h) * WW + w0 + lr) * CC + lq * 4;
#pragma unroll
        for (int g = 0; g < 4; ++g)
            *(f32x4*)(op + g * 16) = acc[g];
    }
}

extern "C" void kernel_launch(void* const* d_in, const int* in_sizes, int n_in,
                              void* d_out, int out_size, void* d_ws, size_t ws_size,
                              hipStream_t stream) {
    const float* x = (const float*)d_in[0];   // [8,384,384] f32
    const float* w = (const float*)d_in[1];   // [49,64] f32
    const float* b = (const float*)d_in[2];   // [64] f32
    float* out = (float*)d_out;               // [8,384,384,64] f32
    (void)in_sizes; (void)n_in; (void)out_size; (void)d_ws; (void)ws_size;
    conv7_mfma_nolds<<<NBLOCKS, 256, 0, stream>>>(x, w, b, out);
}